// Round 1
// baseline (500.304 us; speedup 1.0000x reference)
//
#include <hip/hip_runtime.h>
#include <cstdint>
#include <cstddef>

// ---------------------------------------------------------------------------
// GenEdge: edge = |sum sad*kx| + |sum sad*ky| over 25x25 window of spectral
// angles between 128-dim pixel vectors; normalized by global max.
// Phase 1: f32 -> f16 tiled layout + fp32 norms.
// Phase 2: per (row, 64-col block) wave: banded QK^T via mfma 16x16x32 f16.
// Phase 3: normalize by max, zero 12-px border.
// ---------------------------------------------------------------------------

typedef _Float16 half8 __attribute__((ext_vector_type(8)));
typedef float    f32x4 __attribute__((ext_vector_type(4)));

#define HW   400
#define CCH  128
#define W16  416                 // padded width (26 groups of 16)
#define ROWE (W16*CCH)           // 53248 f16 elements per padded row
#define PAD  12
#define IEND 388                 // interior: [12, 388)

// f16 cube layout per row: [pg(26)][ks(4)][q(4)][i(16)][j(8)] elements
// element (px, ch): pg=px>>4, i=px&15, ks=ch>>5, q=(ch>>3)&3, j=ch&7
// offset = pg*2048 + ks*512 + q*128 + i*8 + j
// => a wave's frag read for (group, ks) is LDS base + lane*16 B (linear),
//    identical to the order global_load_lds writes. No padding needed.

__device__ __forceinline__ void g2lds16(const _Float16* g, _Float16* l) {
  void* gg = (void*)g;  // drop const
  __builtin_amdgcn_global_load_lds(
      (__attribute__((address_space(1))) void*)gg,
      (__attribute__((address_space(3))) void*)l, 16, 0, 0);
}

// ---------------- Phase 1: convert + norms ----------------
__global__ void cvt_kernel(const float* __restrict__ cube,
                           _Float16* __restrict__ c16,
                           float* __restrict__ norms) {
  int pg = blockIdx.x;        // 0..25 (pg 25 is all-pad)
  int r  = blockIdx.y;        // 0..399
  int t  = threadIdx.x;       // 0..255: t = i*16 + ks*4 + q
  int i  = t >> 4;
  int ks = (t >> 2) & 3;
  int q  = t & 3;
  int px = pg*16 + i;
  float v[8];
  if (px < HW) {
    const float* src = cube + ((size_t)(r*HW + px))*CCH + ks*32 + q*8;
    #pragma unroll
    for (int j = 0; j < 8; ++j) v[j] = src[j];
  } else {
    #pragma unroll
    for (int j = 0; j < 8; ++j) v[j] = 0.f;
  }
  half8 hv;
  float ss = 0.f;
  #pragma unroll
  for (int j = 0; j < 8; ++j) { hv[j] = (_Float16)v[j]; ss += v[j]*v[j]; }
  *(half8*)(c16 + (size_t)r*ROWE + pg*2048 + ks*512 + q*128 + i*8) = hv;
  // reduce ss across the 16 lanes sharing pixel i (lane bits 0..3)
  #pragma unroll
  for (int m = 1; m < 16; m <<= 1) ss += __shfl_xor(ss, m);
  if ((t & 15) == 0) norms[r*W16 + px] = (px < HW) ? sqrtf(ss) : 0.f;
}

// ---------------- Phase 2: banded MFMA + SAD accumulation ----------------
__global__ __launch_bounds__(64) void edge_kernel(
    const _Float16* __restrict__ c16, const float* __restrict__ norms,
    float* __restrict__ edge, unsigned* __restrict__ gmax) {
  __shared__ _Float16 slab[6*2048];   // 24576 B: 6 pixel-groups of one row

  const int wb = blockIdx.x;          // 0..5   (w-block)
  const int h  = blockIdx.y + PAD;    // 12..387
  const int l  = threadIdx.x;         // 0..63
  const int c  = l & 15, q = l >> 4;
  const int w0 = PAD + 64*wb;         // first output col of block
  const int g0 = 4*wb;                // first staged pixel-group (s0 = 64*wb)

  // A-frags: center pixels, held for all 25 di.  A[m=lane&15][k=q*8+j]
  half8 A[4][4];
  #pragma unroll
  for (int t = 0; t < 4; ++t) {
    int px = w0 + 16*t + c;           // <= 395 < 400
    const _Float16* p = c16 + (size_t)h*ROWE + (px >> 4)*2048 + q*128 + (px & 15)*8;
    #pragma unroll
    for (int ks = 0; ks < 4; ++ks)
      A[t][ks] = *(const half8*)(p + ks*512);
  }
  // norm_c for this lane's D rows: w = w0 + 16t + 4q + rr
  float nc[4][4];
  #pragma unroll
  for (int t = 0; t < 4; ++t)
    #pragma unroll
    for (int rr = 0; rr < 4; ++rr)
      nc[t][rr] = norms[h*W16 + w0 + 16*t + 4*q + rr];

  float gx[4][4], gy[4][4];
  #pragma unroll
  for (int t = 0; t < 4; ++t)
    #pragma unroll
    for (int rr = 0; rr < 4; ++rr) { gx[t][rr] = 0.f; gy[t][rr] = 0.f; }

  #pragma unroll 1
  for (int di = 0; di < 25; ++di) {
    const int r = h + di - PAD;       // 0..399, always in-bounds
    const _Float16* rowB = c16 + (size_t)r*ROWE + g0*2048;
    // stage 6 groups (24576 B) contiguously: lds dst = base + lane*16
    #pragma unroll
    for (int it = 0; it < 24; ++it)
      g2lds16(rowB + it*512 + l*8, slab + it*512 + l*8);
    __syncthreads();                  // forces vmcnt(0): slab ready

    const float* nr = norms + r*W16 + 64*wb;
    float ns[6];
    #pragma unroll
    for (int n = 0; n < 6; ++n) ns[n] = nr[16*n + c];   // norm_s per N-tile col

    f32x4 acc[4][3];
    #pragma unroll
    for (int t = 0; t < 4; ++t)
      #pragma unroll
      for (int d = 0; d < 3; ++d)
        acc[t][d] = (f32x4){0.f, 0.f, 0.f, 0.f};

    #pragma unroll
    for (int ks = 0; ks < 4; ++ks) {
      half8 B[6];
      #pragma unroll
      for (int n = 0; n < 6; ++n)     // linear, conflict-free ds_read_b128
        B[n] = *(const half8*)(slab + n*2048 + ks*512 + l*8);
      #pragma unroll
      for (int t = 0; t < 4; ++t)
        #pragma unroll
        for (int d = 0; d < 3; ++d)   // band: M-tile t uses N-tiles t..t+2
          acc[t][d] = __builtin_amdgcn_mfma_f32_16x16x32_f16(
              A[t][ks], B[t + d], acc[t][d], 0, 0, 0);
    }

    // epilogue: sad = acos(clip(numer/(nc*ns+1e-4))), weights closed-form
    const int ii  = (di <= 12) ? di : 24 - di;
    const int sdi = (di > 12) - (di < 12);
    #pragma unroll
    for (int t = 0; t < 4; ++t) {
      #pragma unroll
      for (int d = 0; d < 3; ++d) {
        const float nn = ns[t + d];
        #pragma unroll
        for (int rr = 0; rr < 4; ++rr) {
          float numer = acc[t][d][rr];
          int   dj    = 16*d + c - (4*q + rr);       // s - w + 12
          float denom = nc[t][rr]*nn + 1e-4f;
          float ratio = numer * __builtin_amdgcn_rcpf(denom);
          ratio = fminf(fmaxf(ratio, -0.999999f), 0.999999f);
          float sad = acosf(ratio);
          bool  ok  = (dj >= 0) && (dj <= 24);
          int   sdj = (dj > 12) - (dj < 12);
          int   mnj = (dj < 24 - dj) ? dj : 24 - dj;
          float kx  = ok ? (float)(dj - 12 + sdj*ii)  : 0.f;
          float ky  = ok ? (float)(di - 12 + sdi*mnj) : 0.f;
          gx[t][rr] = fmaf(sad, kx, gx[t][rr]);
          gy[t][rr] = fmaf(sad, ky, gy[t][rr]);
        }
      }
    }
    __syncthreads();                  // slab reads done before next stage
  }

  // cross-lane reduce over c (partial C-columns) via LDS scratch
  float* red = (float*)slab;          // 2048 floats = 8 KB, slab is free now
  #pragma unroll
  for (int t = 0; t < 4; ++t)
    #pragma unroll
    for (int rr = 0; rr < 4; ++rr) {
      int p = t*16 + q*4 + rr;
      red[p*16 + c]        = gx[t][rr];
      red[1024 + p*16 + c] = gy[t][rr];
    }
  __syncthreads();
  {
    int p = l;
    float sgx = 0.f, sgy = 0.f;
    #pragma unroll
    for (int cc = 0; cc < 16; ++cc) {
      sgx += red[p*16 + cc];
      sgy += red[1024 + p*16 + cc];
    }
    float e = fabsf(sgx) + fabsf(sgy);
    int tt = p >> 4, qq = (p >> 2) & 3, rr2 = p & 3;
    int w  = w0 + 16*tt + 4*qq + rr2;
    if (w < IEND) edge[h*HW + w] = e;
    else          e = 0.f;            // over-computed right-edge cols
    #pragma unroll
    for (int off = 1; off < 64; off <<= 1) e = fmaxf(e, __shfl_xor(e, off));
    if (l == 0) atomicMax(gmax, __float_as_uint(e));  // e >= 0: uint order ok
  }
}

// ---------------- Phase 3: normalize ----------------
__global__ void norm_kernel(const float* __restrict__ edge,
                            const unsigned* __restrict__ gmax,
                            float* __restrict__ out) {
  int idx = blockIdx.x*256 + threadIdx.x;
  if (idx >= HW*HW) return;
  int hh = idx / HW;
  int ww = idx - hh*HW;
  float mv = __uint_as_float(*gmax);
  float v = 0.f;
  if (hh >= PAD && hh < IEND && ww >= PAD && ww < IEND)
    v = edge[idx] / mv;
  out[idx] = v;
}

// ---------------- launch ----------------
extern "C" void kernel_launch(void* const* d_in, const int* in_sizes, int n_in,
                              void* d_out, int out_size, void* d_ws, size_t ws_size,
                              hipStream_t stream) {
  const float* cube = (const float*)d_in[0];   // (1,400,400,128) f32
  char* ws = (char*)d_ws;
  // ws layout (assumes ws_size >= ~44 MB)
  _Float16* c16   = (_Float16*)(ws);                    // 42,598,400 B
  float*    norms = (float*)(ws + 42598400);            //    665,600 B
  float*    edgeb = (float*)(ws + 43264000);            //    640,000 B
  unsigned* gmax  = (unsigned*)(ws + 43904000);         //          4 B

  hipMemsetAsync(gmax, 0, 4, stream);
  cvt_kernel<<<dim3(26, 400), 256, 0, stream>>>(cube, c16, norms);
  edge_kernel<<<dim3(6, 376), 64, 0, stream>>>(c16, norms, edgeb, gmax);
  norm_kernel<<<(HW*HW + 255)/256, 256, 0, stream>>>(edgeb, gmax, (float*)d_out);
}